// Round 1
// baseline (35.299 us; speedup 1.0000x reference)
//
#include <hip/hip_runtime.h>
#include <math.h>

// VoronoiDecoder: N=65536 points x S=32 seeds.
// Layout: one point per 32-lane half-wave, one seed per lane.
// Pairs (i<j) covered by 16 ring rotations (r=16 half-weighted).

#define EPSF        1e-8f
#define BETA        0.02f
#define ALPHA_UNION 8.0f
#define W_MIN       0.005f
#define W_MAX       0.5f
#define RAW_TEMP    5.0f
#define REL_TEMP    0.05f

__global__ __launch_bounds__(256) void voronoi_rho_kernel(
    const float* __restrict__ points,   // (N,2)
    const float* __restrict__ seeds,    // (32,2)
    const float* __restrict__ w_raw,    // (1,)
    const float* __restrict__ theta,    // (32,)
    const float* __restrict__ a_raw,    // (32,)
    float* __restrict__ out,            // (N,)
    int N)
{
    const int tid = blockIdx.x * blockDim.x + threadIdx.x;
    const int p   = tid >> 5;                 // point index (32 lanes per point)
    const int s   = threadIdx.x & 31;         // seed owned by this lane
    if (p >= N) return;

    // --- scalar band half-width w (same for all) ---
    const float wr = w_raw[0];
    const float w  = W_MIN + (W_MAX - W_MIN) / (1.0f + __expf(-wr * (1.0f / RAW_TEMP)));

    // --- per-lane seed metric M_s = R^T diag(a, 1/a) R ---
    const float t   = tanhf(a_raw[s]);
    const float a   = 0.75f * t + 1.25f;          // 0.5*(A_MAX-A_MIN)*t + 0.5*(A_MAX+A_MIN)
    const float ia  = 1.0f / (a + EPSF);
    float c, sn;
    __sincosf(theta[s], &sn, &c);
    const float M00 = a * c * c + ia * sn * sn;
    const float M01 = c * sn * (ia - a);
    const float M11 = a * sn * sn + ia * c * c;

    // --- anisotropic distance for (point p, seed s), periodic wrap ---
    const float u = points[2 * p];
    const float v = points[2 * p + 1];
    float du = u - seeds[2 * s];     du -= rintf(du);
    float dv = v - seeds[2 * s + 1]; dv -= rintf(dv);
    const float t1 = M00 * du + M01 * dv;
    const float t2 = M01 * du + M11 * dv;
    const float q  = du * t1 + dv * t2;
    const float d  = sqrtf(q + EPSF);

    // --- softmax over the 32 seeds (within the 32-lane group) ---
    float dmin = d;
    #pragma unroll
    for (int m = 16; m >= 1; m >>= 1)
        dmin = fminf(dmin, __shfl_xor(dmin, m, 64));

    const float e = __expf((dmin - d) * (1.0f / REL_TEMP));
    float Z = e;
    #pragma unroll
    for (int m = 16; m >= 1; m >>= 1)
        Z += __shfl_xor(Z, m, 64);
    const float wgt = e * __builtin_amdgcn_rcpf(Z);

    // --- pair loop: 16 ring rotations cover all i<j exactly once ---
    const int lanehi  = threadIdx.x & 32;     // which half of the wave we sit in
    const float invb  = 1.0f / BETA;
    float acc_b = 0.0f;                        // sum_j w_j * B_ij
    float acc_p = 0.0f;                        // sum_j w_j   (pair-mass mirror of ref)
    #pragma unroll
    for (int r = 1; r <= 16; ++r) {
        const int src = lanehi | ((s + r) & 31);
        const float dj = __shfl(d,   src, 64);
        const float wj = __shfl(wgt, src, 64);
        const float Dl = d - dj;
        const float ab = sqrtf(Dl * Dl + EPSF);            // smooth |Δ| (match ref)
        const float B  = __builtin_amdgcn_rcpf(1.0f + __expf((ab - w) * invb));
        const float sc = (r == 16) ? 0.5f : 1.0f;          // r=16 pairs seen twice
        acc_b += sc * wj * B;
        acc_p += sc * wj;
    }

    // --- reduce numerator & pair-mass across the 32 lanes ---
    float nb = wgt * acc_b;
    float dn = wgt * acc_p;
    #pragma unroll
    for (int m = 16; m >= 1; m >>= 1) {
        nb += __shfl_xor(nb, m, 64);
        dn += __shfl_xor(dn, m, 64);
    }

    const float Ssum = nb / (dn + EPSF);
    const float rho  = 1.0f - __expf(-ALPHA_UNION * Ssum);
    if (s == 0) out[p] = rho;
}

extern "C" void kernel_launch(void* const* d_in, const int* in_sizes, int n_in,
                              void* d_out, int out_size, void* d_ws, size_t ws_size,
                              hipStream_t stream) {
    const float* points = (const float*)d_in[0];
    const float* seeds  = (const float*)d_in[1];
    const float* w_raw  = (const float*)d_in[2];
    const float* theta  = (const float*)d_in[3];
    const float* a_raw  = (const float*)d_in[4];
    float* out = (float*)d_out;

    const int N = in_sizes[0] / 2;     // (N,2) points; S fixed at 32 per reference
    const long threads = (long)N * 32;
    const int block = 256;
    const int grid  = (int)((threads + block - 1) / block);

    voronoi_rho_kernel<<<grid, block, 0, stream>>>(points, seeds, w_raw, theta, a_raw, out, N);
}

// Round 2
// 22.143 us; speedup vs baseline: 1.5941x; 1.5941x over previous
//
#include <hip/hip_runtime.h>
#include <math.h>

// VoronoiDecoder: N=65536 points x S=32 seeds.
// Layout: one point per 8 lanes, 4 seeds per lane (float4).
// Pairs (i<j, 496 total) = 6 in-lane + ring rotations r=1..3 (16 each) + r=4 half-weight.
// Seed metrics staged once per block in LDS; d/w exchanged via float4 LDS, same-wave only.

#define EPSF   1e-8f
#define LOG2E  1.4426950408889634f

__global__ __launch_bounds__(256) void voronoi_rho8(
    const float* __restrict__ points,   // (N,2)
    const float* __restrict__ seeds,    // (32,2)
    const float* __restrict__ w_raw,    // (1,)
    const float* __restrict__ theta,    // (32,)
    const float* __restrict__ a_raw,    // (32,)
    float* __restrict__ out,            // (N,)
    int N)
{
    __shared__ float s_su[32], s_sv[32], s_m00[32], s_m01[32], s_m11[32];
    __shared__ float s_d[32 * 32];      // [point_in_block][seed]
    __shared__ float s_w[32 * 32];

    const int t  = threadIdx.x;
    const int pb = t >> 3;              // point within block (0..31)
    const int g  = t & 7;               // seed group (4 seeds each)
    const int p  = blockIdx.x * 32 + pb;

    // --- per-block seed staging: metric M_s and seed uv ---
    if (t < 32) {
        const float tt = tanhf(a_raw[t]);
        const float a  = 0.75f * tt + 1.25f;          // [0.5,2.0] anisotropy
        const float ia = 1.0f / (a + EPSF);
        float sn, cs;
        sincosf(theta[t], &sn, &cs);
        s_m00[t] = a * cs * cs + ia * sn * sn;
        s_m01[t] = cs * sn * (ia - a);
        s_m11[t] = a * sn * sn + ia * cs * cs;
        s_su[t]  = seeds[2 * t];
        s_sv[t]  = seeds[2 * t + 1];
    }
    __syncthreads();

    if (p >= N) return;

    const float u = points[2 * p];
    const float v = points[2 * p + 1];

    // band half-width w (uniform)
    const float wr  = w_raw[0];
    const float sig = __builtin_amdgcn_rcpf(1.0f + exp2f(wr * (-LOG2E / 5.0f)));
    const float w   = 0.005f + 0.495f * sig;

    // --- 4 anisotropic distances (own seed group) ---
    const int s0 = g * 4;
    const float4 su4  = *(const float4*)&s_su[s0];
    const float4 sv4  = *(const float4*)&s_sv[s0];
    const float4 m004 = *(const float4*)&s_m00[s0];
    const float4 m014 = *(const float4*)&s_m01[s0];
    const float4 m114 = *(const float4*)&s_m11[s0];

    float4 d4, e4;
#define DIST(SU, SV, M00, M01, M11, OUTD)                                  \
    {                                                                      \
        float du = u - (SU); du -= rintf(du);                              \
        float dw = v - (SV); dw -= rintf(dw);                              \
        float q  = du * du * (M00) + 2.0f * du * dw * (M01)                \
                 + dw * dw * (M11) + EPSF;                                 \
        (OUTD) = sqrtf(q);                                                 \
    }
    DIST(su4.x, sv4.x, m004.x, m014.x, m114.x, d4.x)
    DIST(su4.y, sv4.y, m004.y, m014.y, m114.y, d4.y)
    DIST(su4.z, sv4.z, m004.z, m014.z, m114.z, d4.z)
    DIST(su4.w, sv4.w, m004.w, m014.w, m114.w, d4.w)

    // --- softmax weights over 32 seeds (no max-sub: exponents >= -29) ---
    const float NEG20L2E = -20.0f * LOG2E;       // 1/REL_TEMP = 20
    e4.x = exp2f(d4.x * NEG20L2E);
    e4.y = exp2f(d4.y * NEG20L2E);
    e4.z = exp2f(d4.z * NEG20L2E);
    e4.w = exp2f(d4.w * NEG20L2E);
    float Z = (e4.x + e4.y) + (e4.z + e4.w);
    Z += __shfl_xor(Z, 1, 64);
    Z += __shfl_xor(Z, 2, 64);
    Z += __shfl_xor(Z, 4, 64);
    const float rcpZ = __builtin_amdgcn_rcpf(Z);
    float4 w4;
    w4.x = e4.x * rcpZ; w4.y = e4.y * rcpZ; w4.z = e4.z * rcpZ; w4.w = e4.w * rcpZ;
    float sumsq = w4.x * w4.x;
    sumsq = fmaf(w4.y, w4.y, sumsq);
    sumsq = fmaf(w4.z, w4.z, sumsq);
    sumsq = fmaf(w4.w, w4.w, sumsq);

    // --- stage d,w to LDS (same-wave exchange; no barrier needed) ---
    float* dbase = &s_d[pb * 32];
    float* wbase = &s_w[pb * 32];
    *(float4*)(dbase + s0) = d4;
    *(float4*)(wbase + s0) = w4;

    // --- pair bodies ---
    const float C1 = 50.0f * LOG2E;              // 1/BETA * log2(e)
    const float C0 = -w * C1;
#define BODY(DI, DJ, WJ, ACC)                                              \
    {                                                                      \
        float ab = fabsf((DI) - (DJ));                                     \
        float ex = exp2f(fmaf(ab, C1, C0));                                \
        float B  = __builtin_amdgcn_rcpf(1.0f + ex);                       \
        (ACC) = fmaf((WJ), B, (ACC));                                      \
    }

    float accb = 0.0f;
    {   // 6 in-lane pairs
        float b0 = 0.0f, b1 = 0.0f, b2 = 0.0f;
        BODY(d4.x, d4.y, w4.y, b0)
        BODY(d4.x, d4.z, w4.z, b0)
        BODY(d4.x, d4.w, w4.w, b0)
        BODY(d4.y, d4.z, w4.z, b1)
        BODY(d4.y, d4.w, w4.w, b1)
        BODY(d4.z, d4.w, w4.w, b2)
        accb = fmaf(w4.x, b0, accb);
        accb = fmaf(w4.y, b1, accb);
        accb = fmaf(w4.z, b2, accb);
    }

#define ROT(R, ACC)                                                        \
    {                                                                      \
        const int gj = (((g + (R)) & 7) * 4);                              \
        const float4 dj = *(const float4*)(dbase + gj);                    \
        const float4 wj = *(const float4*)(wbase + gj);                    \
        float b0 = 0.0f, b1 = 0.0f, b2 = 0.0f, b3 = 0.0f;                  \
        BODY(d4.x, dj.x, wj.x, b0) BODY(d4.x, dj.y, wj.y, b0)              \
        BODY(d4.x, dj.z, wj.z, b0) BODY(d4.x, dj.w, wj.w, b0)              \
        BODY(d4.y, dj.x, wj.x, b1) BODY(d4.y, dj.y, wj.y, b1)              \
        BODY(d4.y, dj.z, wj.z, b1) BODY(d4.y, dj.w, wj.w, b1)              \
        BODY(d4.z, dj.x, wj.x, b2) BODY(d4.z, dj.y, wj.y, b2)              \
        BODY(d4.z, dj.z, wj.z, b2) BODY(d4.z, dj.w, wj.w, b2)              \
        BODY(d4.w, dj.x, wj.x, b3) BODY(d4.w, dj.y, wj.y, b3)              \
        BODY(d4.w, dj.z, wj.z, b3) BODY(d4.w, dj.w, wj.w, b3)              \
        (ACC) = fmaf(w4.x, b0, (ACC));                                     \
        (ACC) = fmaf(w4.y, b1, (ACC));                                     \
        (ACC) = fmaf(w4.z, b2, (ACC));                                     \
        (ACC) = fmaf(w4.w, b3, (ACC));                                     \
    }

    ROT(1, accb)
    ROT(2, accb)
    ROT(3, accb)
    float acc4 = 0.0f;
    ROT(4, acc4)                       // each {g,g+4} pair seen twice
    accb = fmaf(0.5f, acc4, accb);

    // --- reduce over the 8 lanes of this point ---
    float nb = accb, sq = sumsq;
    nb += __shfl_xor(nb, 1, 64);  sq += __shfl_xor(sq, 1, 64);
    nb += __shfl_xor(nb, 2, 64);  sq += __shfl_xor(sq, 2, 64);
    nb += __shfl_xor(nb, 4, 64);  sq += __shfl_xor(sq, 4, 64);

    // analytic pair mass: sum_{i<j} w_i w_j = (1 - sum w^2)/2   (sum w = 1)
    const float den   = fmaxf(0.5f * (1.0f - sq), 0.0f) + EPSF;
    const float ratio = nb * __builtin_amdgcn_rcpf(den);
    const float rho   = 1.0f - exp2f(ratio * (-8.0f * LOG2E));
    if (g == 0) out[p] = rho;
}

extern "C" void kernel_launch(void* const* d_in, const int* in_sizes, int n_in,
                              void* d_out, int out_size, void* d_ws, size_t ws_size,
                              hipStream_t stream) {
    const float* points = (const float*)d_in[0];
    const float* seeds  = (const float*)d_in[1];
    const float* w_raw  = (const float*)d_in[2];
    const float* theta  = (const float*)d_in[3];
    const float* a_raw  = (const float*)d_in[4];
    float* out = (float*)d_out;

    const int N = in_sizes[0] / 2;      // 65536
    const int pointsPerBlock = 32;      // 256 threads / 8 lanes per point
    const int grid = (N + pointsPerBlock - 1) / pointsPerBlock;

    voronoi_rho8<<<grid, 256, 0, stream>>>(points, seeds, w_raw, theta, a_raw, out, N);
}

// Round 3
// 17.575 us; speedup vs baseline: 2.0085x; 1.2599x over previous
//
#include <hip/hip_runtime.h>
#include <math.h>

// VoronoiDecoder: N=65536 points x S=32 seeds.
// 8 lanes/point, 4 seeds/lane. Pair sigmoid B(|d_i-d_j|) via LDS lookup table:
// d quantized to table units at the source (metric pre-scaled by TAB_D^2),
// so each pair = absdiff (3 VALU) + ds_read_b32 + fmac. Zero trans in pair loop.

#define LOG2E  1.4426950408889634f
#define EPSF   1e-8f
#define TAB_D  8192.0f            // table entries per unit distance
#define TAB_N  8320               // max index 8192 + pad
#define BLOCK  512
#define PPB    64                 // points per tile (BLOCK/8)

__device__ __forceinline__ float tabB(const float* tab, unsigned a, unsigned b) {
    const unsigned hi = a > b ? a : b;      // v_max_u32
    const unsigned lo = a > b ? b : a;      // v_min_u32
    return *(const float*)((const char*)tab + (hi - lo));   // byte offsets, mult of 4
}

__global__ __launch_bounds__(BLOCK) void voronoi_tab(
    const float* __restrict__ points,   // (N,2)
    const float* __restrict__ seeds,    // (32,2)
    const float* __restrict__ w_raw,    // (1,)
    const float* __restrict__ theta,    // (32,)
    const float* __restrict__ a_raw,    // (32,)
    float* __restrict__ out,            // (N,)
    int N, int nTiles)
{
    __shared__ float    s_tab[TAB_N];
    __shared__ unsigned s_di[PPB * 32];   // quantized d as byte offsets
    __shared__ float    s_w [PPB * 32];
    __shared__ float    s_su[32], s_sv[32], s_m00[32], s_m01[32], s_m11[32];

    const int t = threadIdx.x;

    // band half-width w (uniform; cheap per thread)
    const float wr = w_raw[0];
    const float sg = __builtin_amdgcn_rcpf(1.0f + exp2f(wr * (-LOG2E / 5.0f)));
    const float w  = 0.005f + 0.495f * sg;

    // --- seed metrics, pre-scaled by TAB_D^2 so sqrt lands in table units ---
    if (t < 32) {
        const float x  = a_raw[t];
        const float z  = exp2f(2.0f * LOG2E * x);                       // e^{2x}
        const float th = (z - 1.0f) * __builtin_amdgcn_rcpf(z + 1.0f);  // tanh(x)
        const float a  = 0.75f * th + 1.25f;
        const float ia = __builtin_amdgcn_rcpf(a + EPSF);
        const float cs = __cosf(theta[t]);
        const float sn = __sinf(theta[t]);
        const float S2 = TAB_D * TAB_D;
        s_m00[t] = (a * cs * cs + ia * sn * sn) * S2;
        s_m01[t] = (cs * sn * (ia - a)) * S2;
        s_m11[t] = (a * sn * sn + ia * cs * cs) * S2;
        s_su[t]  = seeds[2 * t];
        s_sv[t]  = seeds[2 * t + 1];
    }

    // --- sigmoid band table: T[k] = sigmoid((w - k/TAB_D)/BETA) ---
    {
        const float kC = (LOG2E / 0.02f) / TAB_D;
        const float kB = -w * (LOG2E / 0.02f);
        for (int k = t; k < TAB_N; k += BLOCK) {
            const float y = exp2f(fmaf((float)k, kC, kB));
            s_tab[k] = __builtin_amdgcn_rcpf(1.0f + y);
        }
    }
    __syncthreads();   // only barrier; tile loop slabs are same-wave private

    const int pb = t >> 3;           // point slot in block
    const int g  = t & 7;            // seed group (4 seeds)
    const int s0 = g * 4;

    const float4 su4  = *(const float4*)&s_su[s0];
    const float4 sv4  = *(const float4*)&s_sv[s0];
    const float4 m004 = *(const float4*)&s_m00[s0];
    const float4 m014 = *(const float4*)&s_m01[s0];
    const float4 m114 = *(const float4*)&s_m11[s0];

    unsigned* dbase = &s_di[pb * 32];
    float*    wbase = &s_w [pb * 32];

    const float EPS_Q = 1e-8f * TAB_D * TAB_D;      // eps inside sqrt, scaled
    const float cE    = -(20.0f * LOG2E) / TAB_D;   // softmax exponent coef

    for (int tile = blockIdx.x; tile < nTiles; tile += gridDim.x) {
        const int p = tile * PPB + pb;
        if (p < N) {
            const float2 uv = ((const float2*)points)[p];
            const float u = uv.x, v = uv.y;

            float4 d4;
#define DIST(SU, SV, M00, M01, M11, OUTD)                                    \
            {                                                                \
                float du = u - (SU); du -= rintf(du);                        \
                float dv = v - (SV); dv -= rintf(dv);                        \
                float q = fmaf(du * du, (M00),                               \
                          fmaf(2.0f * du * dv, (M01),                       \
                          fmaf(dv * dv, (M11), EPS_Q)));                     \
                (OUTD) = sqrtf(q);                                           \
            }
            DIST(su4.x, sv4.x, m004.x, m014.x, m114.x, d4.x)
            DIST(su4.y, sv4.y, m004.y, m014.y, m114.y, d4.y)
            DIST(su4.z, sv4.z, m004.z, m014.z, m114.z, d4.z)
            DIST(su4.w, sv4.w, m004.w, m014.w, m114.w, d4.w)

            // softmax over 32 seeds (8 lanes x 4); exponents bounded, no max-sub
            float4 e4;
            e4.x = exp2f(d4.x * cE);
            e4.y = exp2f(d4.y * cE);
            e4.z = exp2f(d4.z * cE);
            e4.w = exp2f(d4.w * cE);
            float Z = (e4.x + e4.y) + (e4.z + e4.w);
            Z += __shfl_xor(Z, 1, 64);
            Z += __shfl_xor(Z, 2, 64);
            Z += __shfl_xor(Z, 4, 64);
            const float rcpZ = __builtin_amdgcn_rcpf(Z);
            float4 w4;
            w4.x = e4.x * rcpZ; w4.y = e4.y * rcpZ;
            w4.z = e4.z * rcpZ; w4.w = e4.w * rcpZ;
            float sumsq = w4.x * w4.x;
            sumsq = fmaf(w4.y, w4.y, sumsq);
            sumsq = fmaf(w4.z, w4.z, sumsq);
            sumsq = fmaf(w4.w, w4.w, sumsq);

            // quantize to table byte offsets (round-to-nearest)
            uint4 ii;
            ii.x = ((unsigned)(d4.x + 0.5f)) << 2;
            ii.y = ((unsigned)(d4.y + 0.5f)) << 2;
            ii.z = ((unsigned)(d4.z + 0.5f)) << 2;
            ii.w = ((unsigned)(d4.w + 0.5f)) << 2;

            // stage to this point's private slab (same-wave exchange, no barrier)
            *(uint4*) (dbase + s0) = ii;
            *(float4*)(wbase + s0) = w4;

            // --- pair accumulation: sum w_i w_j B(|d_i-d_j|), i<j over 32 ---
            float accb = 0.0f;
            {   // 6 in-lane pairs
                float b0 = tabB(s_tab, ii.x, ii.y) * w4.y;
                b0 = fmaf(tabB(s_tab, ii.x, ii.z), w4.z, b0);
                b0 = fmaf(tabB(s_tab, ii.x, ii.w), w4.w, b0);
                float b1 = tabB(s_tab, ii.y, ii.z) * w4.z;
                b1 = fmaf(tabB(s_tab, ii.y, ii.w), w4.w, b1);
                float b2 = tabB(s_tab, ii.z, ii.w) * w4.w;
                accb = fmaf(w4.x, b0, accb);
                accb = fmaf(w4.y, b1, accb);
                accb = fmaf(w4.z, b2, accb);
            }

#define ROT(R, ACC)                                                          \
            {                                                                \
                const int gj = ((g + (R)) & 7) * 4;                          \
                const uint4  ij = *(const uint4*) (dbase + gj);              \
                const float4 wj = *(const float4*)(wbase + gj);              \
                float b0, b1, b2, b3;                                        \
                b0 =      tabB(s_tab, ii.x, ij.x) * wj.x;                    \
                b0 = fmaf(tabB(s_tab, ii.x, ij.y), wj.y, b0);                \
                b0 = fmaf(tabB(s_tab, ii.x, ij.z), wj.z, b0);                \
                b0 = fmaf(tabB(s_tab, ii.x, ij.w), wj.w, b0);                \
                b1 =      tabB(s_tab, ii.y, ij.x) * wj.x;                    \
                b1 = fmaf(tabB(s_tab, ii.y, ij.y), wj.y, b1);                \
                b1 = fmaf(tabB(s_tab, ii.y, ij.z), wj.z, b1);                \
                b1 = fmaf(tabB(s_tab, ii.y, ij.w), wj.w, b1);                \
                b2 =      tabB(s_tab, ii.z, ij.x) * wj.x;                    \
                b2 = fmaf(tabB(s_tab, ii.z, ij.y), wj.y, b2);                \
                b2 = fmaf(tabB(s_tab, ii.z, ij.z), wj.z, b2);                \
                b2 = fmaf(tabB(s_tab, ii.z, ij.w), wj.w, b2);                \
                b3 =      tabB(s_tab, ii.w, ij.x) * wj.x;                    \
                b3 = fmaf(tabB(s_tab, ii.w, ij.y), wj.y, b3);                \
                b3 = fmaf(tabB(s_tab, ii.w, ij.z), wj.z, b3);                \
                b3 = fmaf(tabB(s_tab, ii.w, ij.w), wj.w, b3);                \
                (ACC) = fmaf(w4.x, b0, (ACC));                               \
                (ACC) = fmaf(w4.y, b1, (ACC));                               \
                (ACC) = fmaf(w4.z, b2, (ACC));                               \
                (ACC) = fmaf(w4.w, b3, (ACC));                               \
            }

            ROT(1, accb)
            ROT(2, accb)
            ROT(3, accb)
            float acc4 = 0.0f;
            ROT(4, acc4)                     // opposite groups counted twice
            accb = fmaf(0.5f, acc4, accb);

            // reduce over the point's 8 lanes
            float nb = accb, sq = sumsq;
            nb += __shfl_xor(nb, 1, 64);  sq += __shfl_xor(sq, 1, 64);
            nb += __shfl_xor(nb, 2, 64);  sq += __shfl_xor(sq, 2, 64);
            nb += __shfl_xor(nb, 4, 64);  sq += __shfl_xor(sq, 4, 64);

            // pair mass: sum_{i<j} w_i w_j = (1 - sum w^2)/2
            const float den   = fmaxf(0.5f * (1.0f - sq), 0.0f) + EPSF;
            const float ratio = nb * __builtin_amdgcn_rcpf(den);
            const float rho   = 1.0f - exp2f(ratio * (-8.0f * LOG2E));
            if (g == 0) out[p] = rho;
        }
    }
}

extern "C" void kernel_launch(void* const* d_in, const int* in_sizes, int n_in,
                              void* d_out, int out_size, void* d_ws, size_t ws_size,
                              hipStream_t stream) {
    const float* points = (const float*)d_in[0];
    const float* seeds  = (const float*)d_in[1];
    const float* w_raw  = (const float*)d_in[2];
    const float* theta  = (const float*)d_in[3];
    const float* a_raw  = (const float*)d_in[4];
    float* out = (float*)d_out;

    const int N = in_sizes[0] / 2;                 // 65536
    const int nTiles = (N + PPB - 1) / PPB;        // 1024
    const int grid = nTiles < 768 ? nTiles : 768;  // 3 blocks/CU (LDS-limited)

    voronoi_tab<<<grid, BLOCK, 0, stream>>>(points, seeds, w_raw, theta, a_raw,
                                            out, N, nTiles);
}